// Round 3
// baseline (305.809 us; speedup 1.0000x reference)
//
#include <hip/hip_runtime.h>

// Dims (fixed by the reference)
#define NN 1024
// K padded: 64 (ns) + 3 (coords) + 1 (bias) = 68 -> pad to 96 = 3 x 32
#define KP 96
#define LSTR 104   // LDS row stride in shorts (208 B; dword stride 52 -> 2-way banks, free)

typedef __attribute__((ext_vector_type(8))) short short8;
typedef __attribute__((ext_vector_type(4))) short short4v;
typedef __attribute__((ext_vector_type(4))) float f32x4;

__device__ __forceinline__ short f2bf(float f){
  unsigned u = __builtin_bit_cast(unsigned, f);
  u += 0x7FFFu + ((u >> 16) & 1u);       // RNE
  return (short)(u >> 16);
}

// ---------------- fused prep: PT panel (bf16) + B panel + V panel ----------
// blocks 0..95   : PTbf[h][kk][c] = bf16( sum_d Wq[h*1024+d][c] * X[d][kk] )
//                  h = r/12, kk octet = (r%12)*8; no atomics (full d-sum per block)
// blocks 96..159 : Bm[b][m][kk] bf16
// blocks 160..287: Vm[o][kk]   bf16
__global__ __launch_bounds__(256) void prep_all(
    const float* __restrict__ Wq, const float* __restrict__ Wk,
    const float* __restrict__ Wlq, const float* __restrict__ blq,
    const float* __restrict__ ns, const float* __restrict__ coord,
    const float* __restrict__ Wv, const float* __restrict__ Wlv,
    const float* __restrict__ blv,
    short* __restrict__ PTbf, short* __restrict__ Bm, short* __restrict__ Vm){
  __shared__ union SU {
    float red[4][64][9];                       // PT partial sums (pad 9: no conflicts)
    struct { float nsT[64][65]; float cst[3][64]; } bb;
  } S;
  const int t = threadIdx.x;
  const int r = blockIdx.x;

  if (r < 96){
    // ---- PT panel ----
    const int h = r / 12, kidx = r % 12, kk0 = kidx * 8;
    const int c = t & 63, p = t >> 6;            // p: 0..3 d-partitions of 256
    if (kidx > 8){                               // pure pad rows: write zeros
      if (p == 0){
        #pragma unroll
        for (int j = 0; j < 8; ++j) PTbf[(h*96 + kk0 + j)*64 + c] = 0;
      }
      return;
    }
    float acc[8];
    #pragma unroll
    for (int j = 0; j < 8; ++j) acc[j] = 0.f;
    if (kidx < 8){
      #pragma unroll 4
      for (int i = 0; i < 256; ++i){
        const int o = h*1024 + p*256 + i;
        const float wq = Wq[o*64 + c];           // coalesced over c
        const float* wk = Wk + o*64 + kk0;       // wave-uniform row
        f32x4 b0 = *(const f32x4*)(wk);
        f32x4 b1 = *(const f32x4*)(wk + 4);
        #pragma unroll
        for (int j = 0; j < 4; ++j){ acc[j] += wq*b0[j]; acc[4+j] += wq*b1[j]; }
      }
    } else {                                     // kidx==8: kk 64..71 (Wlq/blq/pad)
      #pragma unroll 4
      for (int i = 0; i < 256; ++i){
        const int o = h*1024 + p*256 + i;
        const float wq = Wq[o*64 + c];
        acc[0] += wq * Wlq[o*3 + 0];
        acc[1] += wq * Wlq[o*3 + 1];
        acc[2] += wq * Wlq[o*3 + 2];
        acc[3] += wq * blq[o];
      }
    }
    #pragma unroll
    for (int j = 0; j < 8; ++j) S.red[p][c][j] = acc[j];
    __syncthreads();
    if (p == 0){
      #pragma unroll
      for (int j = 0; j < 8; ++j){
        float s = S.red[0][c][j] + S.red[1][c][j] + S.red[2][c][j] + S.red[3][c][j];
        PTbf[(h*96 + kk0 + j)*64 + c] = f2bf(s);
      }
    }
  } else if (r < 160){
    // ---- B panel ----
    const int rb = r - 96;
    const int b = rb >> 4, m0 = (rb & 15) * 64;
    #pragma unroll
    for (int it = 0; it < 16; ++it){
      int idx = it * 256 + t;
      int c = idx >> 6, mm = idx & 63;
      S.bb.nsT[mm][c] = ns[(b*64 + c)*NN + m0 + mm];   // coalesced over mm
    }
    if (t < 192){
      int j = t >> 6, mm = t & 63;
      S.bb.cst[j][mm] = coord[(b*3 + j)*NN + m0 + mm];
    }
    __syncthreads();
    #pragma unroll
    for (int it = 0; it < 24; ++it){
      int idx = it * 256 + t;                          // 64*96 = 6144
      int mm = idx / KP, kk = idx - mm*KP;
      float v = (kk < 64) ? S.bb.nsT[mm][kk]
              : (kk < 67) ? S.bb.cst[kk - 64][mm]
              : (kk == 67) ? 1.f : 0.f;
      Bm[(b*NN + m0 + mm)*KP + kk] = f2bf(v);
    }
  } else {
    // ---- V panel ----
    const int o0 = (r - 160) * 64;
    #pragma unroll
    for (int it = 0; it < 24; ++it){
      int idx = it * 256 + t;
      int rr = idx / KP, kk = idx - rr*KP;
      int o = o0 + rr;
      float v = (kk < 64) ? Wv[o*64 + kk]
              : (kk < 67) ? Wlv[o*3 + (kk - 64)]
              : (kk == 67) ? blv[o] : 0.f;
      Vm[o*KP + kk] = f2bf(v);
    }
  }
}

// ---------------- K4: fused attention, 32-row n-tiles for occupancy --------
// Per WG: (b,h, 32-row n-block), grid 1024 = exactly 4 WGs/CU at 4 waves/SIMD.
// Each wave owns an m/d QUARTER (256 of 1024) and computes all 32 n-rows
// (2 row fragments af/bn in registers — half the old persistent set, so
// VGPR <= 128 and occupancy doubles: the old 64-row version sat at ~200
// VGPR / 2 waves/SIMD, latency-bound at ~2x its compute+write floor).
// Single-buffered loads (no manual prefetch regs): 4 waves/SIMD TLP +
// compiler load hoisting hide the L2-hit latency.
__global__ __launch_bounds__(256, 4) void attn_main(
    const float* __restrict__ xs, const short* __restrict__ PTbf,
    const short* __restrict__ Bmat, const short* __restrict__ Vm,
    float* __restrict__ out){
  __shared__ short xsL[64 * 32];        // bf16 [c][n_local]  (4 KB)
  __shared__ short AL[32 * LSTR];       // bf16 A rows [n_local][kk] (6.5 KB)
  __shared__ float redS[32 * 4];        // per-row partial sums x 4 waves
  const int t = threadIdx.x, w = t >> 6, lane = t & 63;
  const int q = lane >> 4, ln = lane & 15;
  // XCD chunk swizzle (1024 blocks, 8 XCDs, 128/chunk): each XCD covers
  // bh = x*4..x*4+3 -> one b's B panel + 4 heads' V stay L2-resident.
  const int blk0 = blockIdx.x;
  const int blk = (blk0 & 7) * 128 + (blk0 >> 3);
  const int nb = blk & 31, bh = blk >> 5;
  const int b = bh >> 3, h = bh & 7;
  const int n0 = nb * 32;

  // ---- stage xs[b][0..63][n0..n0+31] as bf16 ----
  const float* xsb = xs + b * 64 * NN;
  #pragma unroll
  for (int it = 0; it < 2; ++it){
    int idx = it * 256 + t;                     // 512 float4 units
    int c = idx >> 3, nn4 = (idx & 7) << 2;
    f32x4 v = *(const f32x4*)(xsb + c * NN + n0 + nn4);
    short4v pk;
    #pragma unroll
    for (int j = 0; j < 4; ++j) pk[j] = f2bf(v[j]);
    *(short4v*)(&xsL[c * 32 + nn4]) = pk;
  }
  __syncthreads();

  // ---- build A (32 rows x 96 kk) via MFMA: A = xs^T . PT^T --------------
  // wave w: row-half rw = (w&1)*16, kt-range kh*3..kh*3+2 (kh = w>>1)
  {
    const int rw = (w & 1) * 16, kh = w >> 1;
    short8 xf0, xf1;
    #pragma unroll
    for (int j = 0; j < 8; ++j){
      xf0[j] = xsL[(q * 8 + j) * 32 + rw + ln];
      xf1[j] = xsL[(32 + q * 8 + j) * 32 + rw + ln];
    }
    const short* PTh = PTbf + h * KP * 64;
    #pragma unroll
    for (int j = 0; j < 3; ++j){
      int kt = kh * 3 + j;
      const short* pr = PTh + (kt * 16 + ln) * 64;
      short8 p0 = *(const short8*)(pr + q * 8);
      short8 p1 = *(const short8*)(pr + 32 + q * 8);
      f32x4 a = {0.f, 0.f, 0.f, 0.f};
      a = __builtin_amdgcn_mfma_f32_16x16x32_bf16(xf0, p0, a, 0, 0, 0);
      a = __builtin_amdgcn_mfma_f32_16x16x32_bf16(xf1, p1, a, 0, 0, 0);
      #pragma unroll
      for (int r = 0; r < 4; ++r)
        AL[(rw + q * 4 + r) * LSTR + kt * 16 + ln] = f2bf(a[r]);
    }
  }
  __syncthreads();

  // ---- persistent fragments: all 32 rows (48 VGPRs) ----
  short8 af[2][3], bn[2][3];
  const short* Bb = Bmat + b * NN * KP;
  #pragma unroll
  for (int rf = 0; rf < 2; ++rf){
    #pragma unroll
    for (int s = 0; s < 3; ++s){
      af[rf][s] = *(const short8*)(&AL[(rf * 16 + ln) * LSTR + s * 32 + q * 8]);
      bn[rf][s] = *(const short8*)(Bb + (n0 + rf * 16 + ln) * KP + s * 32 + q * 8);
    }
  }
  const float KEXP = 0.045084220f;   // log2(e)/32  (SCALE = sqrt(1024) = 32)

  // ---- pass 1: partial row sums over wave's m-quarter (no barriers) ----
  float sum[2][4];
  #pragma unroll
  for (int rf = 0; rf < 2; ++rf)
    #pragma unroll
    for (int r = 0; r < 4; ++r) sum[rf][r] = 0.f;

  {
    const short* bp = Bb + (w * 256 + ln) * KP + q * 8;
    for (int ms = 0; ms < 16; ++ms){
      short8 bf0 = *(const short8*)(bp);
      short8 bf1 = *(const short8*)(bp + 32);
      short8 bf2 = *(const short8*)(bp + 64);
      bp += 16 * KP;
      #pragma unroll
      for (int rf = 0; rf < 2; ++rf){
        f32x4 e = {0.f, 0.f, 0.f, 0.f};
        e = __builtin_amdgcn_mfma_f32_16x16x32_bf16(af[rf][0], bf0, e, 0, 0, 0);
        e = __builtin_amdgcn_mfma_f32_16x16x32_bf16(af[rf][1], bf1, e, 0, 0, 0);
        e = __builtin_amdgcn_mfma_f32_16x16x32_bf16(af[rf][2], bf2, e, 0, 0, 0);
        #pragma unroll
        for (int r = 0; r < 4; ++r)
          sum[rf][r] += __builtin_amdgcn_exp2f(e[r] * KEXP);
      }
    }
  }
  // reduce over the 16 m-columns (ln bits), then across waves via LDS
  #pragma unroll
  for (int rf = 0; rf < 2; ++rf){
    #pragma unroll
    for (int r = 0; r < 4; ++r){
      float s = sum[rf][r];
      s += __shfl_xor(s, 1); s += __shfl_xor(s, 2);
      s += __shfl_xor(s, 4); s += __shfl_xor(s, 8);
      if (ln == 0) redS[(rf * 16 + q * 4 + r) * 4 + w] = s;
    }
  }
  __syncthreads();
  float rinv[2][4];
  #pragma unroll
  for (int rf = 0; rf < 2; ++rf){
    #pragma unroll
    for (int r = 0; r < 4; ++r){
      f32x4 v4 = *(const f32x4*)(&redS[(rf * 16 + q * 4 + r) * 4]);
      rinv[rf][r] = 1.0f / (v4[0] + v4[1] + v4[2] + v4[3]);
    }
  }

  // ---- pass 2: wave's d-quarter, recompute e + vc GEMM, store ------------
  // Stores: rf=0,1 cover 32 contiguous cols = 128 B per row per iter,
  // 128-B aligned -> full lines, no write amplification.
  {
    const short* Vh = Vm + h * 1024 * KP;
    const short* bp = Bb + (w * 256 + ln) * KP + q * 8;
    const short* vp = Vh + (w * 256 + ln) * KP + q * 8;
    float* op = out + (size_t)bh * (1024 * 1024) + (w * 256 + ln) * NN + n0;
    for (int ds = 0; ds < 16; ++ds){
      short8 bf0 = *(const short8*)(bp);
      short8 bf1 = *(const short8*)(bp + 32);
      short8 bf2 = *(const short8*)(bp + 64);
      short8 vf0 = *(const short8*)(vp);
      short8 vf1 = *(const short8*)(vp + 32);
      short8 vf2 = *(const short8*)(vp + 64);
      bp += 16 * KP; vp += 16 * KP;
      #pragma unroll
      for (int rf = 0; rf < 2; ++rf){
        f32x4 e  = {0.f, 0.f, 0.f, 0.f};
        f32x4 vv = {0.f, 0.f, 0.f, 0.f};
        e  = __builtin_amdgcn_mfma_f32_16x16x32_bf16(af[rf][0], bf0, e, 0, 0, 0);
        e  = __builtin_amdgcn_mfma_f32_16x16x32_bf16(af[rf][1], bf1, e, 0, 0, 0);
        e  = __builtin_amdgcn_mfma_f32_16x16x32_bf16(af[rf][2], bf2, e, 0, 0, 0);
        vv = __builtin_amdgcn_mfma_f32_16x16x32_bf16(bn[rf][0], vf0, vv, 0, 0, 0);
        vv = __builtin_amdgcn_mfma_f32_16x16x32_bf16(bn[rf][1], vf1, vv, 0, 0, 0);
        vv = __builtin_amdgcn_mfma_f32_16x16x32_bf16(bn[rf][2], vf2, vv, 0, 0, 0);
        f32x4 o;
        #pragma unroll
        for (int r = 0; r < 4; ++r)
          o[r] = __builtin_amdgcn_exp2f(e[r] * KEXP) * rinv[rf][r] * vv[r];
        *(f32x4*)(op + rf * 16 + q * 4) = o;
      }
      op += 16 * NN;
    }
  }
}

extern "C" void kernel_launch(void* const* d_in, const int* in_sizes, int n_in,
                              void* d_out, int out_size, void* d_ws, size_t ws_size,
                              hipStream_t stream){
  const float* coord = (const float*)d_in[0];
  const float* x     = (const float*)d_in[1];
  const float* nbr   = (const float*)d_in[2];
  const float* Wq    = (const float*)d_in[3];
  const float* Wk    = (const float*)d_in[4];
  const float* Wv    = (const float*)d_in[5];
  const float* Wlq   = (const float*)d_in[6];
  const float* blq   = (const float*)d_in[7];
  const float* Wlv   = (const float*)d_in[8];
  const float* blv   = (const float*)d_in[9];
  float* out = (float*)d_out;

  char* ws = (char*)d_ws;
  short* PTbf = (short*)ws;                       // 8*96*64*2   =   98304 B
  short* Bm   = (short*)(ws + 98304);             // 4*1024*96*2 =  786432 B
  short* Vm   = (short*)(ws + 98304 + 786432);    // 8*1024*96*2 = 1572864 B
  // total ws: 2,457,600 B

  prep_all<<<288, 256, 0, stream>>>(Wq, Wk, Wlq, blq, nbr, coord, Wv, Wlv, blv,
                                    PTbf, Bm, Vm);
  attn_main<<<1024, 256, 0, stream>>>(x, PTbf, Bm, Vm, out);
}

// Round 4
// 245.926 us; speedup vs baseline: 1.2435x; 1.2435x over previous
//
#include <hip/hip_runtime.h>

// Dims (fixed by the reference)
#define NN 1024
// K padded: 64 (ns) + 3 (coords) + 1 (bias) = 68 -> pad to 96 = 3 x 32
#define KP 96
#define LSTR 104   // LDS row stride in shorts (208 B; 16-B aligned rows)

typedef __attribute__((ext_vector_type(8))) short short8;
typedef __attribute__((ext_vector_type(4))) short short4v;
typedef __attribute__((ext_vector_type(4))) float f32x4;

__device__ __forceinline__ short f2bf(float f){
  unsigned u = __builtin_bit_cast(unsigned, f);
  u += 0x7FFFu + ((u >> 16) & 1u);       // RNE
  return (short)(u >> 16);
}

// ---------------- fused prep: PT panel (bf16) + B panel + V panel ----------
// blocks 0..95   : PTbf[h][kk][c] = bf16( sum_d Wq[h*1024+d][c] * X[d][kk] )
//                  h = r/12, kk octet = (r%12)*8; no atomics (full d-sum per block)
// blocks 96..159 : Bm[b][m][kk] bf16
// blocks 160..287: Vm[o][kk]   bf16
__global__ __launch_bounds__(256) void prep_all(
    const float* __restrict__ Wq, const float* __restrict__ Wk,
    const float* __restrict__ Wlq, const float* __restrict__ blq,
    const float* __restrict__ ns, const float* __restrict__ coord,
    const float* __restrict__ Wv, const float* __restrict__ Wlv,
    const float* __restrict__ blv,
    short* __restrict__ PTbf, short* __restrict__ Bm, short* __restrict__ Vm){
  __shared__ union SU {
    float red[4][64][9];                       // PT partial sums (pad 9: no conflicts)
    struct { float nsT[64][65]; float cst[3][64]; } bb;
  } S;
  const int t = threadIdx.x;
  const int r = blockIdx.x;

  if (r < 96){
    // ---- PT panel ----
    const int h = r / 12, kidx = r % 12, kk0 = kidx * 8;
    const int c = t & 63, p = t >> 6;            // p: 0..3 d-partitions of 256
    if (kidx > 8){                               // pure pad rows: write zeros
      if (p == 0){
        #pragma unroll
        for (int j = 0; j < 8; ++j) PTbf[(h*96 + kk0 + j)*64 + c] = 0;
      }
      return;
    }
    float acc[8];
    #pragma unroll
    for (int j = 0; j < 8; ++j) acc[j] = 0.f;
    if (kidx < 8){
      #pragma unroll 4
      for (int i = 0; i < 256; ++i){
        const int o = h*1024 + p*256 + i;
        const float wq = Wq[o*64 + c];           // coalesced over c
        const float* wk = Wk + o*64 + kk0;       // wave-uniform row
        f32x4 b0 = *(const f32x4*)(wk);
        f32x4 b1 = *(const f32x4*)(wk + 4);
        #pragma unroll
        for (int j = 0; j < 4; ++j){ acc[j] += wq*b0[j]; acc[4+j] += wq*b1[j]; }
      }
    } else {                                     // kidx==8: kk 64..71 (Wlq/blq/pad)
      #pragma unroll 4
      for (int i = 0; i < 256; ++i){
        const int o = h*1024 + p*256 + i;
        const float wq = Wq[o*64 + c];
        acc[0] += wq * Wlq[o*3 + 0];
        acc[1] += wq * Wlq[o*3 + 1];
        acc[2] += wq * Wlq[o*3 + 2];
        acc[3] += wq * blq[o];
      }
    }
    #pragma unroll
    for (int j = 0; j < 8; ++j) S.red[p][c][j] = acc[j];
    __syncthreads();
    if (p == 0){
      #pragma unroll
      for (int j = 0; j < 8; ++j){
        float s = S.red[0][c][j] + S.red[1][c][j] + S.red[2][c][j] + S.red[3][c][j];
        PTbf[(h*96 + kk0 + j)*64 + c] = f2bf(s);
      }
    }
  } else if (r < 160){
    // ---- B panel ----
    const int rb = r - 96;
    const int b = rb >> 4, m0 = (rb & 15) * 64;
    #pragma unroll
    for (int it = 0; it < 16; ++it){
      int idx = it * 256 + t;
      int c = idx >> 6, mm = idx & 63;
      S.bb.nsT[mm][c] = ns[(b*64 + c)*NN + m0 + mm];   // coalesced over mm
    }
    if (t < 192){
      int j = t >> 6, mm = t & 63;
      S.bb.cst[j][mm] = coord[(b*3 + j)*NN + m0 + mm];
    }
    __syncthreads();
    #pragma unroll
    for (int it = 0; it < 24; ++it){
      int idx = it * 256 + t;                          // 64*96 = 6144
      int mm = idx / KP, kk = idx - mm*KP;
      float v = (kk < 64) ? S.bb.nsT[mm][kk]
              : (kk < 67) ? S.bb.cst[kk - 64][mm]
              : (kk == 67) ? 1.f : 0.f;
      Bm[(b*NN + m0 + mm)*KP + kk] = f2bf(v);
    }
  } else {
    // ---- V panel ----
    const int o0 = (r - 160) * 64;
    #pragma unroll
    for (int it = 0; it < 24; ++it){
      int idx = it * 256 + t;
      int rr = idx / KP, kk = idx - rr*KP;
      int o = o0 + rr;
      float v = (kk < 64) ? Wv[o*64 + kk]
              : (kk < 67) ? Wlv[o*3 + (kk - 64)]
              : (kk == 67) ? blv[o] : 0.f;
      Vm[o*KP + kk] = f2bf(v);
    }
  }
}

// ---------------- K4: fused attention, 8-wave WGs, 64-col n-tiles ----------
// Per WG: (b,h, 64-col n-block), 512 threads = 8 waves; grid 512 = 2 WGs/CU
// -> 16 waves/CU (round-2 was grid-limited to 8). Each wave owns an m/d
// EIGHTH (128 of 1024 rows). 64-col tiles keep stores at 256 B per output
// row per ds-iter (256-B HBM write granule: 128-B tiles measured 2x write
// amplification + RFO fetch in round 3).
// VGPR diet to fit 128 (4 waves/SIMD): no manual double-buffer; bn fragments
// live in an LDS copy of the n-block's B rows (re-read per ds-iter); rinv
// read from LDS per-rf.
__global__ __launch_bounds__(512, 4) void attn_main(
    const float* __restrict__ xs, const short* __restrict__ PTbf,
    const short* __restrict__ Bmat, const short* __restrict__ Vm,
    float* __restrict__ out){
  __shared__ short xsL[64 * 64];        // bf16 [c][n_local]  (8 KB)
  __shared__ short AL[64 * LSTR];       // bf16 A rows [n_local][kk] (13.3 KB)
  __shared__ short BL[64 * LSTR];       // bf16 B rows n0..n0+63 (13.3 KB)
  __shared__ float redS[64 * 9];        // per-row partial sums x 8 waves (pad 9)
  __shared__ float rinvS[64];           // 1/rowsum
  const int t = threadIdx.x, w = t >> 6, lane = t & 63;
  const int q = lane >> 4, ln = lane & 15;
  // XCD chunk swizzle (512 blocks, 8 XCDs, 64/chunk): XCD x covers bh
  // 4x..4x+3 -> one b's B panel + 4 heads' V stay L2-resident.
  const int blk0 = blockIdx.x;
  const int blk = (blk0 & 7) * 64 + (blk0 >> 3);
  const int nb = blk & 15, bh = blk >> 4;
  const int b = bh >> 3, h = bh & 7;
  const int n0 = nb * 64;

  // ---- stage xs[b][0..63][n0..n0+63] as bf16 ----
  const float* xsb = xs + b * 64 * NN;
  #pragma unroll
  for (int it = 0; it < 2; ++it){
    int idx = it * 512 + t;                     // 1024 float4 units
    int c = idx >> 4, nn4 = (idx & 15) << 2;
    f32x4 v = *(const f32x4*)(xsb + c * NN + n0 + nn4);
    short4v pk;
    #pragma unroll
    for (int j = 0; j < 4; ++j) pk[j] = f2bf(v[j]);
    *(short4v*)(&xsL[c * 64 + nn4]) = pk;
  }
  const short* Bb = Bmat + b * NN * KP;
  // ---- stage B rows n0..n0+63 into BL (bn operands for pass 2) ----
  #pragma unroll
  for (int it = 0; it < 2; ++it){
    int idx = it * 512 + t;                     // 768 short8 units
    if (idx < 768){
      int row = idx / 12, s8 = idx - row * 12;
      *(short8*)(&BL[row * LSTR + s8 * 8]) =
          *(const short8*)(Bb + (n0 + row) * KP + s8 * 8);
    }
  }
  __syncthreads();

  // ---- build A (64 rows x 96 kk) via MFMA: A = xs^T . PT^T --------------
  // wave w: rows (w&3)*16..+15, kt-range (w>>2)*3..+2
  {
    const int rw = (w & 3) * 16, kh = w >> 2;
    short8 xf0, xf1;
    #pragma unroll
    for (int j = 0; j < 8; ++j){
      xf0[j] = xsL[(q * 8 + j) * 64 + rw + ln];
      xf1[j] = xsL[(32 + q * 8 + j) * 64 + rw + ln];
    }
    const short* PTh = PTbf + h * KP * 64;
    #pragma unroll
    for (int j = 0; j < 3; ++j){
      int kt = kh * 3 + j;
      const short* pr = PTh + (kt * 16 + ln) * 64;
      short8 p0 = *(const short8*)(pr + q * 8);
      short8 p1 = *(const short8*)(pr + 32 + q * 8);
      f32x4 a = {0.f, 0.f, 0.f, 0.f};
      a = __builtin_amdgcn_mfma_f32_16x16x32_bf16(xf0, p0, a, 0, 0, 0);
      a = __builtin_amdgcn_mfma_f32_16x16x32_bf16(xf1, p1, a, 0, 0, 0);
      #pragma unroll
      for (int r = 0; r < 4; ++r)
        AL[(rw + q * 4 + r) * LSTR + kt * 16 + ln] = f2bf(a[r]);
    }
  }
  __syncthreads();

  // ---- persistent A fragments: all 64 rows (48 VGPRs) ----
  short8 af[4][3];
  #pragma unroll
  for (int rf = 0; rf < 4; ++rf)
    #pragma unroll
    for (int s = 0; s < 3; ++s)
      af[rf][s] = *(const short8*)(&AL[(rf * 16 + ln) * LSTR + s * 32 + q * 8]);
  const float KEXP = 0.045084220f;   // log2(e)/32  (SCALE = sqrt(1024) = 32)

  // ---- pass 1: partial row sums over wave's m-eighth (no barriers) ----
  float sum[4][4];
  #pragma unroll
  for (int rf = 0; rf < 4; ++rf)
    #pragma unroll
    for (int r = 0; r < 4; ++r) sum[rf][r] = 0.f;

  {
    const short* bp = Bb + (w * 128 + ln) * KP + q * 8;
    for (int ms = 0; ms < 8; ++ms){
      short8 bf0 = *(const short8*)(bp);
      short8 bf1 = *(const short8*)(bp + 32);
      short8 bf2 = *(const short8*)(bp + 64);
      bp += 16 * KP;
      #pragma unroll
      for (int rf = 0; rf < 4; ++rf){
        f32x4 e = {0.f, 0.f, 0.f, 0.f};
        e = __builtin_amdgcn_mfma_f32_16x16x32_bf16(af[rf][0], bf0, e, 0, 0, 0);
        e = __builtin_amdgcn_mfma_f32_16x16x32_bf16(af[rf][1], bf1, e, 0, 0, 0);
        e = __builtin_amdgcn_mfma_f32_16x16x32_bf16(af[rf][2], bf2, e, 0, 0, 0);
        #pragma unroll
        for (int r = 0; r < 4; ++r)
          sum[rf][r] += __builtin_amdgcn_exp2f(e[r] * KEXP);
      }
    }
  }
  // reduce over 16 m-columns (ln bits), then across 8 waves via LDS
  #pragma unroll
  for (int rf = 0; rf < 4; ++rf){
    #pragma unroll
    for (int r = 0; r < 4; ++r){
      float s = sum[rf][r];
      s += __shfl_xor(s, 1); s += __shfl_xor(s, 2);
      s += __shfl_xor(s, 4); s += __shfl_xor(s, 8);
      if (ln == 0) redS[(rf * 16 + q * 4 + r) * 9 + w] = s;
    }
  }
  __syncthreads();
  if (t < 64){
    float s = 0.f;
    #pragma unroll
    for (int ww = 0; ww < 8; ++ww) s += redS[t * 9 + ww];
    rinvS[t] = 1.0f / s;
  }
  __syncthreads();

  // ---- pass 2: wave's d-eighth, recompute e + vc GEMM, store -------------
  // (Recompute costs ~5 us of MFMA chip-wide; caching P needs 128 VGPRs or
  //  500 MB of extra traffic — both measured worse.)
  {
    const short* Vh = Vm + h * 1024 * KP;
    const short* bp = Bb + (w * 128 + ln) * KP + q * 8;
    const short* vp = Vh + (w * 128 + ln) * KP + q * 8;
    float* op = out + (size_t)bh * (1024 * 1024) + (w * 128 + ln) * NN + n0;
    for (int ds = 0; ds < 8; ++ds){
      short8 bf0 = *(const short8*)(bp);
      short8 bf1 = *(const short8*)(bp + 32);
      short8 bf2 = *(const short8*)(bp + 64);
      short8 vf0 = *(const short8*)(vp);
      short8 vf1 = *(const short8*)(vp + 32);
      short8 vf2 = *(const short8*)(vp + 64);
      bp += 16 * KP; vp += 16 * KP;
      #pragma unroll
      for (int rf = 0; rf < 4; ++rf){
        const short* blp = &BL[(rf * 16 + ln) * LSTR + q * 8];
        short8 bn0 = *(const short8*)(blp);
        short8 bn1 = *(const short8*)(blp + 32);
        short8 bn2 = *(const short8*)(blp + 64);
        f32x4 e  = {0.f, 0.f, 0.f, 0.f};
        f32x4 vv = {0.f, 0.f, 0.f, 0.f};
        e  = __builtin_amdgcn_mfma_f32_16x16x32_bf16(af[rf][0], bf0, e, 0, 0, 0);
        e  = __builtin_amdgcn_mfma_f32_16x16x32_bf16(af[rf][1], bf1, e, 0, 0, 0);
        e  = __builtin_amdgcn_mfma_f32_16x16x32_bf16(af[rf][2], bf2, e, 0, 0, 0);
        vv = __builtin_amdgcn_mfma_f32_16x16x32_bf16(bn0, vf0, vv, 0, 0, 0);
        vv = __builtin_amdgcn_mfma_f32_16x16x32_bf16(bn1, vf1, vv, 0, 0, 0);
        vv = __builtin_amdgcn_mfma_f32_16x16x32_bf16(bn2, vf2, vv, 0, 0, 0);
        f32x4 ri = *(const f32x4*)(&rinvS[rf * 16 + q * 4]);
        f32x4 o;
        #pragma unroll
        for (int r = 0; r < 4; ++r)
          o[r] = __builtin_amdgcn_exp2f(e[r] * KEXP) * ri[r] * vv[r];
        // rows d0+ln, cols n0 + rf*16 + q*4..+3 (rf loop covers 256 B/row)
        *(f32x4*)(op + rf * 16 + q * 4) = o;
      }
      op += 16 * NN;
    }
  }
}

extern "C" void kernel_launch(void* const* d_in, const int* in_sizes, int n_in,
                              void* d_out, int out_size, void* d_ws, size_t ws_size,
                              hipStream_t stream){
  const float* coord = (const float*)d_in[0];
  const float* x     = (const float*)d_in[1];
  const float* nbr   = (const float*)d_in[2];
  const float* Wq    = (const float*)d_in[3];
  const float* Wk    = (const float*)d_in[4];
  const float* Wv    = (const float*)d_in[5];
  const float* Wlq   = (const float*)d_in[6];
  const float* blq   = (const float*)d_in[7];
  const float* Wlv   = (const float*)d_in[8];
  const float* blv   = (const float*)d_in[9];
  float* out = (float*)d_out;

  char* ws = (char*)d_ws;
  short* PTbf = (short*)ws;                       // 8*96*64*2   =   98304 B
  short* Bm   = (short*)(ws + 98304);             // 4*1024*96*2 =  786432 B
  short* Vm   = (short*)(ws + 98304 + 786432);    // 8*1024*96*2 = 1572864 B
  // total ws: 2,457,600 B

  prep_all<<<288, 256, 0, stream>>>(Wq, Wk, Wlq, blq, nbr, coord, Wv, Wlv, blv,
                                    PTbf, Bm, Vm);
  attn_main<<<512, 512, 0, stream>>>(x, PTbf, Bm, Vm, out);
}